// Round 9
// baseline (137.879 us; speedup 1.0000x reference)
//
#include <hip/hip_runtime.h>
#include <hip/hip_bf16.h>
#include <math.h>

#define MARGIN_F 6.0f
// phase = pr / (REL_RANGE/PI) = pr * (PI / 0.03125)
#define PHASE_SCALE 100.53096491487338f

// ---------------------------------------------------------------------------
// K1: fused prep. grid = 16 blocks (one per b), 1024 threads (16 waves).
//  - mean-pool qh[b] (64x768) -> q[768] in LDS
//  - linear 768->18 + sigmoid (one wave per relation)
//  - mixture -> phase -> sincos -> head gather -> complex rotate
// rot layout in ws: rot_re[16][256] at float offset 0, rot_im at 4096.
// ---------------------------------------------------------------------------
__global__ void k_prep(const float* __restrict__ qh, const float* __restrict__ W,
                       const float* __restrict__ brel,
                       const float* __restrict__ rel,
                       const float* __restrict__ ent, const int* __restrict__ hid,
                       float* __restrict__ rot) {
    __shared__ float q[768];
    __shared__ float sig[18];
    int b = blockIdx.x;
    int t = threadIdx.x;

    if (t < 768) {
        float s = 0.f;
        const float* base = qh + (size_t)b * 64 * 768 + t;
        #pragma unroll 8
        for (int srow = 0; srow < 64; ++srow) s += base[(size_t)srow * 768];
        q[t] = s * (1.0f / 64.0f);
    }
    __syncthreads();

    int wave = t >> 6, lane = t & 63;
    for (int r = wave; r < 18; r += 16) {
        float p = 0.f;
        for (int h = lane; h < 768; h += 64) p += q[h] * W[r * 768 + h];
        for (int off = 32; off; off >>= 1) p += __shfl_xor(p, off, 64);
        if (lane == 0) sig[r] = 1.0f / (1.0f + expf(-(p + brel[r])));
    }
    __syncthreads();

    if (t < 256) {
        int d = t;
        float pr = 0.f;
        #pragma unroll
        for (int r = 0; r < 18; ++r) pr += sig[r] * rel[r * 256 + d];
        float phase = pr * PHASE_SCALE;
        float sn, cs;
        sincosf(phase, &sn, &cs);
        int h0 = hid[b];
        float reh = ent[(size_t)h0 * 512 + d];
        float imh = ent[(size_t)h0 * 512 + 256 + d];
        rot[b * 256 + d]        = reh * cs - imh * sn;  // rot_re
        rot[4096 + b * 256 + d] = reh * sn + imh * cs;  // rot_im
    }
}

// ---------------------------------------------------------------------------
// K2 (new structure): lane = entity, d-sum fully in-lane. Block (4 waves,
// 256 thr) owns 64 entities; entity rows staged coalesced into LDS in
// d-chunks of 64. Wave w computes b=4w..4w+3 with acc[4][2] (8 VGPR — nothing
// for the allocator to demote). rot reads are wave-uniform -> scalarized.
// Zero shuffles, zero compaction, direct coalesced stores.
// LDS [64][33] float2: b64 reads hit the 4-cycle BW floor with balanced banks.
// ---------------------------------------------------------------------------
#define TILE 64
#define CHUNK 64  // dims per chunk
#define NCHUNK 4  // 256 / CHUNK

__global__ __launch_bounds__(256, 4) void k_dist(const float* __restrict__ ent,
                                                 const float* __restrict__ rot,
                                                 float* __restrict__ out, int E) {
    __shared__ float2 lre[TILE][CHUNK / 2 + 1];  // [64][33]
    __shared__ float2 lim[TILE][CHUNK / 2 + 1];

    int t = threadIdx.x;
    int lane = t & 63;
    int w = t >> 6;  // wave 0..3 owns b = 4w..4w+3
    int e0 = blockIdx.x * TILE;
    int ei = e0 + lane;

    const float2* rot2 = (const float2*)rot;  // re at f2 idx b*128+d2, im at +2048

    float acc[4][2];
    #pragma unroll
    for (int j = 0; j < 4; ++j) acc[j][0] = acc[j][1] = 0.f;

    for (int c = 0; c < NCHUNK; ++c) {
        __syncthreads();  // previous chunk's readers done before overwrite
        // stage 64 rows x 64 dims x {re,im}: 2048 float4-slots, 8 per thread
        #pragma unroll
        for (int pass = 0; pass < 8; ++pass) {
            int slot = pass * 256 + t;  // 0..2047
            int half = slot >> 10;      // 0 = re, 1 = im
            int within = slot & 1023;
            int row = within >> 4;  // 0..63
            int k = within & 15;    // float4 index within chunk
            int er = min(e0 + row, E - 1);
            const float4* g =
                (const float4*)(ent + (size_t)er * 512 + half * 256 + c * CHUNK);
            float4 v = g[k];
            float2* dst = (half ? lim[row] : lre[row]) + k * 2;
            dst[0] = make_float2(v.x, v.y);
            dst[1] = make_float2(v.z, v.w);
        }
        __syncthreads();

        #pragma unroll 8
        for (int p = 0; p < CHUNK / 2; ++p) {
            float2 te = lre[lane][p];
            float2 ti = lim[lane][p];
            #pragma unroll
            for (int j = 0; j < 4; ++j) {
                int b = w * 4 + j;
                size_t ro = (size_t)b * 128 + c * (CHUNK / 2) + p;
                float2 rr = rot2[ro];         // wave-uniform -> s_load
                float2 ri = rot2[2048 + ro];  // wave-uniform -> s_load
                float dx0 = rr.x - te.x, dy0 = ri.x - ti.x;
                float dx1 = rr.y - te.y, dy1 = ri.y - ti.y;
                acc[j][0] += __builtin_amdgcn_sqrtf(dx0 * dx0 + dy0 * dy0);
                acc[j][1] += __builtin_amdgcn_sqrtf(dx1 * dx1 + dy1 * dy1);
            }
        }
    }

    if (ei < E) {
        #pragma unroll
        for (int j = 0; j < 4; ++j)
            out[(size_t)(w * 4 + j) * E + ei] =
                MARGIN_F - (acc[j][0] + acc[j][1]);
    }
}

extern "C" void kernel_launch(void* const* d_in, const int* in_sizes, int n_in,
                              void* d_out, int out_size, void* d_ws,
                              size_t ws_size, hipStream_t stream) {
    const float* qh   = (const float*)d_in[0];  // (16,64,768)
    const float* W    = (const float*)d_in[1];  // (18,768)
    const float* brel = (const float*)d_in[2];  // (18,)
    const float* rel  = (const float*)d_in[3];  // (18,256)
    const float* ent  = (const float*)d_in[4];  // (E,512)
    const int*   hid  = (const int*)d_in[5];    // (16,)
    float* out = (float*)d_out;

    int E = in_sizes[4] / 512;

    float* rot = (float*)d_ws;  // 2*16*256 floats = 32 KB

    k_prep<<<dim3(16), 1024, 0, stream>>>(qh, W, brel, rel, ent, hid, rot);

    int nblk = (E + TILE - 1) / TILE;  // 676 blocks of 64 entities
    k_dist<<<dim3(nblk), 256, 0, stream>>>(ent, rot, out, E);
}

// Round 10
// 58.795 us; speedup vs baseline: 2.3451x; 2.3451x over previous
//
#include <hip/hip_runtime.h>
#include <hip/hip_bf16.h>
#include <math.h>

#define MARGIN_F 6.0f
// phase = pr / (REL_RANGE/PI) = pr * (PI / 0.03125)
#define PHASE_SCALE 100.53096491487338f

// ---------------------------------------------------------------------------
// K1: fused prep. grid = 16 blocks (one per b), 1024 threads (16 waves).
// rot layout in ws: rot_re[16][256] at float offset 0, rot_im at 4096.
// ---------------------------------------------------------------------------
__global__ void k_prep(const float* __restrict__ qh, const float* __restrict__ W,
                       const float* __restrict__ brel,
                       const float* __restrict__ rel,
                       const float* __restrict__ ent, const int* __restrict__ hid,
                       float* __restrict__ rot) {
    __shared__ float q[768];
    __shared__ float sig[18];
    int b = blockIdx.x;
    int t = threadIdx.x;

    if (t < 768) {
        float s = 0.f;
        const float* base = qh + (size_t)b * 64 * 768 + t;
        #pragma unroll 8
        for (int srow = 0; srow < 64; ++srow) s += base[(size_t)srow * 768];
        q[t] = s * (1.0f / 64.0f);
    }
    __syncthreads();

    int wave = t >> 6, lane = t & 63;
    for (int r = wave; r < 18; r += 16) {
        float p = 0.f;
        for (int h = lane; h < 768; h += 64) p += q[h] * W[r * 768 + h];
        for (int off = 32; off; off >>= 1) p += __shfl_xor(p, off, 64);
        if (lane == 0) sig[r] = 1.0f / (1.0f + expf(-(p + brel[r])));
    }
    __syncthreads();

    if (t < 256) {
        int d = t;
        float pr = 0.f;
        #pragma unroll
        for (int r = 0; r < 18; ++r) pr += sig[r] * rel[r * 256 + d];
        float phase = pr * PHASE_SCALE;
        float sn, cs;
        sincosf(phase, &sn, &cs);
        int h0 = hid[b];
        float reh = ent[(size_t)h0 * 512 + d];
        float imh = ent[(size_t)h0 * 512 + 256 + d];
        rot[b * 256 + d]        = reh * cs - imh * sn;  // rot_re
        rot[4096 + b * 256 + d] = reh * sn + imh * cs;  // rot_im
    }
}

// ---------------------------------------------------------------------------
// K2: 4 waves/block, wave w owns b = 4w..4w+3; block covers b=0..15 over a
// contiguous entity chunk. The 8 rot float4 fragments (32 VGPR) are loaded
// ONCE and pinned via empty asm ("+v") — the compiler cannot rematerialize
// them from L1 inside the loop (the failure mode of rounds 4/6/7/8, which
// made the loop L1-BW-bound at ~44 us). G=2 entities per iteration so the
// two independent 7-shuffle reduce chains interleave (halves DS latency
// exposure). lane l owns dims 4l..4l+3; entity row = 2 coalesced float4.
// ---------------------------------------------------------------------------
__global__ __launch_bounds__(256, 4) void k_dist(const float* __restrict__ ent,
                                                 const float* __restrict__ rot,
                                                 float* __restrict__ out, int E,
                                                 int chunk) {
    int lane = threadIdx.x & 63;
    int w4 = threadIdx.x >> 6;  // which 4 b's this wave owns

    const float4* rre4 = (const float4*)rot + (size_t)w4 * 4 * 64;
    const float4* rim4 = (const float4*)(rot + 4096) + (size_t)w4 * 4 * 64;
    float4 ra[4], ia[4];
    #pragma unroll
    for (int b = 0; b < 4; ++b) {
        ra[b] = rre4[b * 64 + lane];
        ia[b] = rim4[b * 64 + lane];
    }
    // Pin the 32 fragment VGPRs: values become opaque asm results, so the
    // backend cannot turn them back into per-iteration L1 loads.
    #pragma unroll
    for (int b = 0; b < 4; ++b) {
        asm volatile("" : "+v"(ra[b].x), "+v"(ra[b].y), "+v"(ra[b].z), "+v"(ra[b].w));
        asm volatile("" : "+v"(ia[b].x), "+v"(ia[b].y), "+v"(ia[b].z), "+v"(ia[b].w));
    }

    // b owned by lane l (<4) after compaction: b = 2*l0 + l1 (round-8 mapping)
    int bout = w4 * 4 + (((lane & 1) << 1) | ((lane >> 1) & 1));

    int e0 = blockIdx.x * chunk;
    int e1 = min(e0 + chunk, E);

    for (int e = e0; e < e1; e += 2) {
        int ea = e;
        int eb = min(e + 1, e1 - 1);  // tail: duplicate load, store guarded
        const float4* r4a = (const float4*)(ent + (size_t)ea * 512);
        const float4* r4b = (const float4*)(ent + (size_t)eb * 512);
        float4 tea = r4a[lane], tia = r4a[64 + lane];
        float4 teb = r4b[lane], tib = r4b[64 + lane];

        float va[4], vb[4];
        #pragma unroll
        for (int b = 0; b < 4; ++b) {
            float dx0 = ra[b].x - tea.x, dy0 = ia[b].x - tia.x;
            float dx1 = ra[b].y - tea.y, dy1 = ia[b].y - tia.y;
            float dx2 = ra[b].z - tea.z, dy2 = ia[b].z - tia.z;
            float dx3 = ra[b].w - tea.w, dy3 = ia[b].w - tia.w;
            float s0 = __builtin_amdgcn_sqrtf(dx0 * dx0 + dy0 * dy0);
            float s1 = __builtin_amdgcn_sqrtf(dx1 * dx1 + dy1 * dy1);
            float s2 = __builtin_amdgcn_sqrtf(dx2 * dx2 + dy2 * dy2);
            float s3 = __builtin_amdgcn_sqrtf(dx3 * dx3 + dy3 * dy3);
            va[b] = (s0 + s1) + (s2 + s3);

            float ex0 = ra[b].x - teb.x, ey0 = ia[b].x - tib.x;
            float ex1 = ra[b].y - teb.y, ey1 = ia[b].y - tib.y;
            float ex2 = ra[b].z - teb.z, ey2 = ia[b].z - tib.z;
            float ex3 = ra[b].w - teb.w, ey3 = ia[b].w - tib.w;
            float u0 = __builtin_amdgcn_sqrtf(ex0 * ex0 + ey0 * ey0);
            float u1 = __builtin_amdgcn_sqrtf(ex1 * ex1 + ey1 * ey1);
            float u2 = __builtin_amdgcn_sqrtf(ex2 * ex2 + ey2 * ey2);
            float u3 = __builtin_amdgcn_sqrtf(ex3 * ex3 + ey3 * ey3);
            vb[b] = (u0 + u1) + (u2 + u3);
        }

        // two independent compaction reduces (4 vals x 64 lanes -> lanes 0..3)
        #pragma unroll
        for (int i = 0; i < 2; ++i) {
            float sa = (lane & 1) ? va[i] : va[i + 2];
            float sb = (lane & 1) ? vb[i] : vb[i + 2];
            float ca = __shfl_xor(sa, 1, 64);
            float cb = __shfl_xor(sb, 1, 64);
            va[i] = ((lane & 1) ? va[i + 2] : va[i]) + ca;
            vb[i] = ((lane & 1) ? vb[i + 2] : vb[i]) + cb;
        }
        {
            float sa = (lane & 2) ? va[0] : va[1];
            float sb = (lane & 2) ? vb[0] : vb[1];
            float ca = __shfl_xor(sa, 2, 64);
            float cb = __shfl_xor(sb, 2, 64);
            va[0] = ((lane & 2) ? va[1] : va[0]) + ca;
            vb[0] = ((lane & 2) ? vb[1] : vb[0]) + cb;
        }
        va[0] += __shfl_xor(va[0], 4, 64);
        vb[0] += __shfl_xor(vb[0], 4, 64);
        va[0] += __shfl_xor(va[0], 8, 64);
        vb[0] += __shfl_xor(vb[0], 8, 64);
        va[0] += __shfl_xor(va[0], 16, 64);
        vb[0] += __shfl_xor(vb[0], 16, 64);
        va[0] += __shfl_xor(va[0], 32, 64);
        vb[0] += __shfl_xor(vb[0], 32, 64);

        if (lane < 4) {
            out[(size_t)bout * E + ea] = MARGIN_F - va[0];
            if (e + 1 < e1) out[(size_t)bout * E + e + 1] = MARGIN_F - vb[0];
        }
    }
}

extern "C" void kernel_launch(void* const* d_in, const int* in_sizes, int n_in,
                              void* d_out, int out_size, void* d_ws,
                              size_t ws_size, hipStream_t stream) {
    const float* qh   = (const float*)d_in[0];  // (16,64,768)
    const float* W    = (const float*)d_in[1];  // (18,768)
    const float* brel = (const float*)d_in[2];  // (18,)
    const float* rel  = (const float*)d_in[3];  // (18,256)
    const float* ent  = (const float*)d_in[4];  // (E,512)
    const int*   hid  = (const int*)d_in[5];    // (16,)
    float* out = (float*)d_out;

    int E = in_sizes[4] / 512;

    float* rot = (float*)d_ws;  // 2*16*256 floats = 32 KB

    k_prep<<<dim3(16), 1024, 0, stream>>>(qh, W, brel, rel, ent, hid, rot);

    const int NB = 2048;            // 8192 waves = 8/SIMD
    int chunk = (E + NB - 1) / NB;  // ~22 consecutive entities per block
    k_dist<<<dim3(NB), 256, 0, stream>>>(ent, rot, out, E, chunk);
}